// Round 6
// baseline (316.755 us; speedup 1.0000x reference)
//
#include <hip/hip_runtime.h>
#include <cmath>

#define NN 100000
#define EE 1600000
#define NB 1563          // ceil(NN/64) buckets of 64 dst nodes
#define CAP 1344         // per-bucket edge capacity (mean 1024, sigma 32)
#define EPB 25           // edges per thread in bin path (256 blk * 256 thr * 25)
#define NTILE 6250       // NN/16
#define PROJB 1563       // ceil(NTILE/4) proj blocks
#define CVTB 3125        // h->bf16 conversion blocks (256 thr * 8 elems)

using bf16x8 = __attribute__((ext_vector_type(8))) __bf16;
using f32x4  = __attribute__((ext_vector_type(4))) float;

__device__ __forceinline__ unsigned short f2bf(float f) {
  __bf16 b = (__bf16)f;
  return __builtin_bit_cast(unsigned short, b);
}
__device__ __forceinline__ float bflo(unsigned int u) {
  return __uint_as_float(u << 16);
}
__device__ __forceinline__ float bfhi(unsigned int u) {
  return __uint_as_float(u & 0xffff0000u);
}
__device__ __forceinline__ float sigmoidf_(float v) {
  return 1.0f / (1.0f + __expf(-v));
}
// fast tanh: exact at +-inf, ~1e-6 abs err, far below bf16 quantization
__device__ __forceinline__ float tanhfast(float v) {
  return 1.0f - 2.0f / (1.0f + __expf(2.0f * v));
}
__device__ __forceinline__ bf16x8 cvt8(float4 a, float4 b) {
  bf16x8 r;
  r[0]=(__bf16)a.x; r[1]=(__bf16)a.y; r[2]=(__bf16)a.z; r[3]=(__bf16)a.w;
  r[4]=(__bf16)b.x; r[5]=(__bf16)b.y; r[6]=(__bf16)b.z; r[7]=(__bf16)b.w;
  return r;
}

// ---- K0: weight prep ----
// wperm rows are stored GRANULE-SWIZZLED for conflict-free LDS reads in
// k_lstm: logical 16B granule gl = kf*4+quad of row p lives at physical
// granule gl ^ (p&15).  (Linear global->LDS copy preserves the swizzle.)
__global__ __launch_bounds__(128) void k_prep(
    const float* __restrict__ Wih, const float* __restrict__ Whh,
    const float* __restrict__ Wg,
    unsigned short* __restrict__ wperm, unsigned short* __restrict__ wgp)
{
  if (blockIdx.x < 256) {
    const int p = blockIdx.x, k = threadIdx.x;
    const int g = p & 3;
    const int h = (p >> 4) + ((p >> 2) & 3) * 16;
    const int row = g*64 + h;
    const float v = (k < 64) ? Wih[row*64 + k] : Whh[row*64 + (k - 64)];
    const int gp = (k >> 3) ^ (p & 15);           // swizzled granule
    wperm[p*128 + gp*8 + (k & 7)] = f2bf(v);
  } else {
    for (int idx = threadIdx.x; idx < 4096; idx += 128) {
      const int lane = idx >> 6, r = idx & 63;
      const int nt = r >> 4, kf = (r >> 3) & 1, j = r & 7;
      const int m = lane & 15, quad = lane >> 4;
      wgp[idx] = f2bf(Wg[(kf*32 + quad*8 + j)*64 + nt*16 + m]);
    }
  }
}

// ---- K1: grid-fused {edge binning | xs = x @ W_gat + att dots | h->bf16} --
__global__ __launch_bounds__(256) void k_binproj(
    const int* __restrict__ ei, int* __restrict__ bcursor,
    unsigned int* __restrict__ binned,
    const float* __restrict__ x, const unsigned short* __restrict__ wgp,
    const float* __restrict__ att_s, const float* __restrict__ att_d,
    unsigned short* __restrict__ xs16, float* __restrict__ a_src,
    float* __restrict__ a_dst,
    const float* __restrict__ h0, unsigned short* __restrict__ h16)
{
  if (blockIdx.x < 256) {
    // ---------------- bin path ----------------
    __shared__ int cnt[NB];
    __shared__ int gbase[NB];
    const int tid = threadIdx.x;
    const size_t base = (size_t)blockIdx.x * 256 * EPB;

    for (int b = tid; b < NB; b += 256) cnt[b] = 0;
    __syncthreads();

    unsigned int pay[EPB];
    int bidx[EPB], pos[EPB];
    #pragma unroll
    for (int j = 0; j < EPB; ++j) {
      const size_t e = base + (size_t)j*256 + tid;
      if (e < EE) {
        const int s = ei[e];
        const int d = ei[EE + e];
        bidx[j] = d >> 6;
        pay[j] = (unsigned)s | ((unsigned)(d & 63) << 17);
        pos[j] = atomicAdd(&cnt[bidx[j]], 1);
      } else {
        bidx[j] = -1;
      }
    }
    __syncthreads();

    for (int b = tid; b < NB; b += 256) {
      const int c = cnt[b];
      gbase[b] = c ? atomicAdd(&bcursor[b*16], c) : 0;
    }
    __syncthreads();

    #pragma unroll
    for (int j = 0; j < EPB; ++j) {
      if (bidx[j] >= 0) {
        const int g = gbase[bidx[j]] + pos[j];
        if (g < CAP) binned[(size_t)bidx[j]*CAP + g] = pay[j];
      }
    }
  } else if (blockIdx.x < 256 + PROJB) {
    // ---------------- proj path ----------------
    const int lane = threadIdx.x & 63;
    const int wave = threadIdx.x >> 6;
    const int tile = (blockIdx.x - 256) * 4 + wave;
    if (tile >= NTILE) return;
    const int m = lane & 15, quad = lane >> 4;

    bf16x8 bfrag[4][2];
    {
      const unsigned short* wp = wgp + lane*64;
      #pragma unroll
      for (int nt = 0; nt < 4; ++nt)
        #pragma unroll
        for (int kf = 0; kf < 2; ++kf)
          bfrag[nt][kf] = *(const bf16x8*)(wp + nt*16 + kf*8);
    }

    const int row = tile*16 + m;
    bf16x8 afrag[2];
    #pragma unroll
    for (int kf = 0; kf < 2; ++kf) {
      const float4* p = (const float4*)(x + (size_t)row*64 + kf*32 + quad*8);
      afrag[kf] = cvt8(p[0], p[1]);
    }

    f32x4 acc[4];
    #pragma unroll
    for (int nt = 0; nt < 4; ++nt) acc[nt] = f32x4{0.f, 0.f, 0.f, 0.f};
    #pragma unroll
    for (int nt = 0; nt < 4; ++nt)
      #pragma unroll
      for (int kf = 0; kf < 2; ++kf)
        acc[nt] = __builtin_amdgcn_mfma_f32_16x16x32_bf16(
            afrag[kf], bfrag[nt][kf], acc[nt], 0, 0, 0);

    float ss[4] = {0.f,0.f,0.f,0.f}, sd[4] = {0.f,0.f,0.f,0.f};
    #pragma unroll
    for (int nt = 0; nt < 4; ++nt) {
      const float av = att_s[nt*16 + m], dv = att_d[nt*16 + m];
      #pragma unroll
      for (int r = 0; r < 4; ++r) {
        const float v = acc[nt][r];
        xs16[(size_t)(tile*16 + quad*4 + r)*64 + nt*16 + m] = f2bf(v);
        ss[r] += v * av;
        sd[r] += v * dv;
      }
    }
    #pragma unroll
    for (int off = 1; off < 16; off <<= 1) {
      #pragma unroll
      for (int r = 0; r < 4; ++r) {
        ss[r] += __shfl_xor(ss[r], off);
        sd[r] += __shfl_xor(sd[r], off);
      }
    }
    if (m == 0) {
      #pragma unroll
      for (int r = 0; r < 4; ++r) {
        a_src[tile*16 + quad*4 + r] = ss[r];
        a_dst[tile*16 + quad*4 + r] = sd[r];
      }
    }
  } else {
    // ---------------- h -> bf16 path ----------------
    const int idx = (blockIdx.x - 256 - PROJB)*256 + threadIdx.x;  // 0..799999
    const float* p = h0 + (size_t)idx*8;
    const bf16x8 v = cvt8(*(const float4*)p, *(const float4*)(p + 4));
    *(bf16x8*)(h16 + (size_t)idx*8) = v;
  }
}

// ---- K3: fused CSR build + softmax aggregation, one block per bucket.
// Round-6: SRC-SWEEP locality.  CSR key extended from dst to (dst, src>>11)
// via 4096 packed-u16 counters + in-LDS scan, so every node's edge list is
// src-ascending.  All ~1563 co-resident blocks then sweep xs16 in the same
// order -> the 12.8 MB gather working set collapses to a narrow moving
// window that fits per-XCD L2.  Pass 4 is the proven round-4 single-stream
// loop (round-5's 4-stream predication regressed).
__global__ __launch_bounds__(256) void k_agg(
    const int* __restrict__ bcursor, const unsigned int* __restrict__ binned,
    const float* __restrict__ a_src, const float* __restrict__ a_dst,
    const unsigned short* __restrict__ xs16, const float* __restrict__ bias,
    unsigned short* __restrict__ xb16)
{
  __shared__ unsigned int parray[CAP];   // p bits per edge (pass1 -> pass3)
  __shared__ uint2 csre[CAP];            // {src, p bits}, (dst,srcbin)-sorted
  __shared__ unsigned int cnt[2048];     // 4096 u16 counters/offsets, packed
  __shared__ float zsum[64], invzsh[64], adsh[64];
  __shared__ int base64[64], deg64[64];
  __shared__ unsigned int wtot[4];
  const int b = blockIdx.x;
  const int tid = threadIdx.x;
  const int ne = min(bcursor[b*16], CAP);

  for (int i = tid; i < 2048; i += 256) cnt[i] = 0;
  if (tid < 64) {
    zsum[tid] = 0.f;
    const int node = b*64 + tid;
    adsh[tid] = (node < NN) ? a_dst[node] : 0.f;
  }
  __syncthreads();

  // pass 1: MLP-unrolled edge-parallel p + (dst,srcbin) count + z
  {
    unsigned int w6[6];
    float as6[6];
    #pragma unroll
    for (int k = 0; k < 6; ++k) {
      const int i = tid + k*256;
      w6[k] = (i < ne) ? binned[(size_t)b*CAP + i] : 0u;
    }
    #pragma unroll
    for (int k = 0; k < 6; ++k) {
      const int i = tid + k*256;
      as6[k] = (i < ne) ? a_src[w6[k] & 0x1FFFFu] : 0.f;
    }
    #pragma unroll
    for (int k = 0; k < 6; ++k) {
      const int i = tid + k*256;
      if (i < ne) {
        const unsigned int s = w6[k] & 0x1FFFFu;
        const int dl = (int)((w6[k] >> 17) & 63u);
        float ev = as6[k] + adsh[dl];
        ev = (ev >= 0.f) ? ev : 0.2f*ev;
        const float pv = __expf(ev);
        parray[i] = __float_as_uint(pv);
        const int key = dl*64 + (int)(s >> 11);
        atomicAdd(&cnt[key >> 1], (key & 1) ? 0x10000u : 1u);
        atomicAdd(&zsum[dl], pv);
      }
    }
  }
  __syncthreads();

  // pass 2a: in-place exclusive scan of the 4096 packed u16 counts.
  // Thread t exclusively owns u32s [t*8, t*8+8) = keys [t*16, t*16+16).
  {
    unsigned int loc[8];
    unsigned int sum = 0;
    #pragma unroll
    for (int j = 0; j < 8; ++j) {
      loc[j] = cnt[tid*8 + j];
      sum += (loc[j] & 0xffffu) + (loc[j] >> 16);
    }
    const int lane = tid & 63, wv = tid >> 6;
    unsigned int run = sum;
    #pragma unroll
    for (int off = 1; off < 64; off <<= 1) {
      const unsigned int o = __shfl_up(run, off, 64);
      if (lane >= off) run += o;
    }
    if (lane == 63) wtot[wv] = run;
    __syncthreads();
    unsigned int wbase = 0;
    for (int w2 = 0; w2 < wv; ++w2) wbase += wtot[w2];
    unsigned int ex = wbase + run - sum;   // exclusive base for this thread
    #pragma unroll
    for (int j = 0; j < 8; ++j) {
      const unsigned int lo = loc[j] & 0xffffu, hi = loc[j] >> 16;
      cnt[tid*8 + j] = ex | ((ex + lo) << 16);
      ex += lo + hi;
    }
  }
  __syncthreads();

  // pass 2b: per-node base/degree + 1/z (before scatter destroys cnt)
  if (tid < 64) {
    const int b0 = (int)(cnt[(tid*64) >> 1] & 0xffffu);          // key even
    const int e0 = (tid == 63) ? ne : (int)(cnt[((tid+1)*64) >> 1] & 0xffffu);
    base64[tid] = b0;
    deg64[tid] = e0 - b0;
    invzsh[tid] = 1.f / (zsum[tid] + 1e-16f);
  }
  __syncthreads();

  // pass 3: scatter {s,p} to (dst,srcbin)-sorted CSR; cnt doubles as cursor
  #pragma unroll
  for (int k = 0; k < 6; ++k) {
    const int i = tid + k*256;
    if (i < ne) {
      const unsigned int w = binned[(size_t)b*CAP + i];   // L2-hot re-read
      const unsigned int s = w & 0x1FFFFu;
      const int dl = (int)((w >> 17) & 63u);
      const int key = dl*64 + (int)(s >> 11);
      const unsigned int old = atomicAdd(&cnt[key >> 1], (key & 1) ? 0x10000u : 1u);
      const int pos = (int)((key & 1) ? (old >> 16) : (old & 0xffffu));
      csre[pos] = make_uint2(s, parray[i]);
    }
  }
  __syncthreads();

  // pass 4: aggregation (round-4 single-stream form); edge lists are
  // src-ascending so all groups sweep xs16 in lockstep.
  const int lane = tid & 63;
  const int wv = tid >> 6;
  const int grp = lane >> 4, l16 = lane & 15;
  const float4 b4 = *(const float4*)(bias + l16*4);
  const unsigned short* xrow = xs16 + l16*4;
  for (int t = 0; t < 16; ++t) {
    const int nl = wv*16 + t;
    const int node = b*64 + nl;
    if (node >= NN) break;
    const int bse = base64[nl];
    const int dg = deg64[nl];
    float acc0=0.f, acc1=0.f, acc2=0.f, acc3=0.f;
    for (int e = grp; e < dg; e += 4) {
      const uint2 sp = csre[bse + e];
      const float pv = __uint_as_float(sp.y);
      const uint2 rw = *(const uint2*)(xrow + (size_t)sp.x*64);
      acc0 += pv*bflo(rw.x); acc1 += pv*bfhi(rw.x);
      acc2 += pv*bflo(rw.y); acc3 += pv*bfhi(rw.y);
    }
    #pragma unroll
    for (int off = 16; off < 64; off <<= 1) {
      acc0 += __shfl_xor(acc0, off);
      acc1 += __shfl_xor(acc1, off);
      acc2 += __shfl_xor(acc2, off);
      acc3 += __shfl_xor(acc3, off);
    }
    if (lane < 16) {
      const float invz = invzsh[nl];
      ushort4 o;
      o.x = f2bf(tanhfast(acc0*invz + b4.x));
      o.y = f2bf(tanhfast(acc1*invz + b4.y));
      o.z = f2bf(tanhfast(acc2*invz + b4.z));
      o.w = f2bf(tanhfast(acc3*invz + b4.w));
      *(ushort4*)(xb16 + (size_t)node*64 + l16*4) = o;
    }
  }
}

// ---- K4: LSTM with LDS-resident weights (unchanged from round 3).
__global__ __launch_bounds__(1024, 2) void k_lstm(
    const unsigned short* __restrict__ xb16, const unsigned short* __restrict__ h16,
    const float* __restrict__ c0, const unsigned short* __restrict__ wperm,
    float* __restrict__ out)
{
  __shared__ unsigned short wlds[256*128];   // 64 KB, swizzled layout
  const int tid = threadIdx.x;
  {
    const float4* gs = (const float4*)wperm;
    float4* ls = (float4*)wlds;
    #pragma unroll
    for (int i = 0; i < 4; ++i) ls[tid + i*1024] = gs[tid + i*1024];
  }
  __syncthreads();

  const int w = tid >> 6, lane = tid & 63;
  const int wv = w & 3, tsub = w >> 2;
  const int m = lane & 15, quad = lane >> 4;
  const int tile = blockIdx.x*4 + tsub;
  if (tile >= NTILE) return;
  const int node = tile*16 + m;

  bf16x8 bfr[4];
  bfr[0] = *(const bf16x8*)(xb16 + (size_t)node*64 + quad*8);
  bfr[1] = *(const bf16x8*)(xb16 + (size_t)node*64 + 32 + quad*8);
  bfr[2] = *(const bf16x8*)(h16 + (size_t)node*64 + quad*8);
  bfr[3] = *(const bf16x8*)(h16 + (size_t)node*64 + 32 + quad*8);

  const int q32 = (m >> 2) & 3;
  const int base = (wv*64 + m)*256 + ((quad ^ (m & 3)) << 4);
  const char* lb = (const char*)wlds;
  const int a0 = base + ((0 ^ q32) << 6);
  const int a1 = base + ((1 ^ q32) << 6);
  const int a2 = base + ((2 ^ q32) << 6);
  const int a3 = base + ((3 ^ q32) << 6);

  f32x4 acc[4];
  #pragma unroll
  for (int u = 0; u < 4; ++u) acc[u] = f32x4{0.f, 0.f, 0.f, 0.f};
  #pragma unroll
  for (int u = 0; u < 4; ++u) {
    const int uo = u*4096;
    const bf16x8 w0 = *(const bf16x8*)(lb + a0 + uo);
    const bf16x8 w1 = *(const bf16x8*)(lb + a1 + uo);
    const bf16x8 w2 = *(const bf16x8*)(lb + a2 + uo);
    const bf16x8 w3 = *(const bf16x8*)(lb + a3 + uo);
    acc[u] = __builtin_amdgcn_mfma_f32_16x16x32_bf16(w0, bfr[0], acc[u], 0, 0, 0);
    acc[u] = __builtin_amdgcn_mfma_f32_16x16x32_bf16(w1, bfr[1], acc[u], 0, 0, 0);
    acc[u] = __builtin_amdgcn_mfma_f32_16x16x32_bf16(w2, bfr[2], acc[u], 0, 0, 0);
    acc[u] = __builtin_amdgcn_mfma_f32_16x16x32_bf16(w3, bfr[3], acc[u], 0, 0, 0);
  }

  const size_t obase = (size_t)node*64 + quad*16 + wv*4;
  const float4 cv = *(const float4*)(c0 + obase);
  const float cvv[4] = {cv.x, cv.y, cv.z, cv.w};
  float h1a[4], c1a[4];
  #pragma unroll
  for (int u = 0; u < 4; ++u) {
    const float gi = acc[u][0], gf = acc[u][1];
    const float gg = acc[u][2], go = acc[u][3];
    const float c1 = sigmoidf_(gf)*cvv[u] + sigmoidf_(gi)*tanhfast(gg);
    h1a[u] = sigmoidf_(go)*tanhfast(c1);
    c1a[u] = c1;
  }
  const float4 hv  = make_float4(h1a[0], h1a[1], h1a[2], h1a[3]);
  const float4 c1v = make_float4(c1a[0], c1a[1], c1a[2], c1a[3]);
  *(float4*)(out + obase) = hv;
  *(float4*)(out + (size_t)NN*64 + obase) = hv;
  *(float4*)(out + (size_t)2*NN*64 + obase) = c1v;
}

// ---------------- launch ---------------------------------------------------
extern "C" void kernel_launch(void* const* d_in, const int* in_sizes, int n_in,
                              void* d_out, int out_size, void* d_ws, size_t ws_size,
                              hipStream_t stream) {
  const float* x    = (const float*)d_in[0];
  const int*   ei   = (const int*)d_in[1];
  const float* h    = (const float*)d_in[2];
  const float* c    = (const float*)d_in[3];
  const float* Wg   = (const float*)d_in[4];
  const float* atts = (const float*)d_in[5];
  const float* attd = (const float*)d_in[6];
  const float* bg   = (const float*)d_in[7];
  const float* Wih  = (const float*)d_in[8];
  const float* Whh  = (const float*)d_in[9];
  float* out = (float*)d_out;

  char* w = (char*)d_ws;
  unsigned short* xs16  = (unsigned short*)w; w += (size_t)NN*64*2;
  unsigned short* xb16  = (unsigned short*)w; w += (size_t)NN*64*2;
  unsigned short* h16   = (unsigned short*)w; w += (size_t)NN*64*2;
  unsigned short* wperm = (unsigned short*)w; w += (size_t)256*128*2;
  unsigned short* wgp   = (unsigned short*)w; w += (size_t)4096*2;
  unsigned int*   binned= (unsigned int*)w;  w += (size_t)NB*CAP*4;
  float* a_src = (float*)w; w += (size_t)NN*4;
  float* a_dst = (float*)w; w += (size_t)NN*4;
  int* bcursor = (int*)w;   w += (size_t)NB*16*4;   // 64B-padded cursors

  hipMemsetAsync(bcursor, 0, (size_t)NB*16*4, stream);

  k_prep    <<<257, 128, 0, stream>>>(Wih, Whh, Wg, wperm, wgp);
  k_binproj <<<256 + PROJB + CVTB, 256, 0, stream>>>(
      ei, bcursor, binned, x, wgp, atts, attd, xs16, a_src, a_dst, h, h16);
  k_agg     <<<NB, 256, 0, stream>>>(bcursor, binned, a_src, a_dst, xs16, bg, xb16);
  k_lstm    <<<PROJB, 1024, 0, stream>>>(xb16, h16, c, wperm, out);
}

// Round 7
// 303.834 us; speedup vs baseline: 1.0425x; 1.0425x over previous
//
#include <hip/hip_runtime.h>
#include <cmath>

#define NN 100000
#define EE 1600000
#define NB 1563          // ceil(NN/64) buckets of 64 dst nodes
#define CAP 1344         // per-bucket edge capacity (mean 1024, sigma 32)
#define EPB 25           // edges per thread in bin path (256 blk * 256 thr * 25)
#define NTILE 6250       // NN/16
#define PROJB 1563       // ceil(NTILE/4) proj blocks
#define CVTB 3125        // h->bf16 conversion blocks (256 thr * 8 elems)

using bf16x8 = __attribute__((ext_vector_type(8))) __bf16;
using f32x4  = __attribute__((ext_vector_type(4))) float;

__device__ __forceinline__ unsigned short f2bf(float f) {
  __bf16 b = (__bf16)f;
  return __builtin_bit_cast(unsigned short, b);
}
__device__ __forceinline__ float bflo(unsigned int u) {
  return __uint_as_float(u << 16);
}
__device__ __forceinline__ float bfhi(unsigned int u) {
  return __uint_as_float(u & 0xffff0000u);
}
__device__ __forceinline__ float sigmoidf_(float v) {
  return 1.0f / (1.0f + __expf(-v));
}
// fast tanh: exact at +-inf, ~1e-6 abs err, far below bf16 quantization
__device__ __forceinline__ float tanhfast(float v) {
  return 1.0f - 2.0f / (1.0f + __expf(2.0f * v));
}
__device__ __forceinline__ bf16x8 cvt8(float4 a, float4 b) {
  bf16x8 r;
  r[0]=(__bf16)a.x; r[1]=(__bf16)a.y; r[2]=(__bf16)a.z; r[3]=(__bf16)a.w;
  r[4]=(__bf16)b.x; r[5]=(__bf16)b.y; r[6]=(__bf16)b.z; r[7]=(__bf16)b.w;
  return r;
}

// ---- K0: weight prep ----
// wperm rows are stored GRANULE-SWIZZLED for conflict-free LDS reads in
// k_lstm: logical 16B granule gl = kf*4+quad of row p lives at physical
// granule gl ^ (p&15).  (Linear global->LDS copy preserves the swizzle.)
__global__ __launch_bounds__(128) void k_prep(
    const float* __restrict__ Wih, const float* __restrict__ Whh,
    const float* __restrict__ Wg,
    unsigned short* __restrict__ wperm, unsigned short* __restrict__ wgp)
{
  if (blockIdx.x < 256) {
    const int p = blockIdx.x, k = threadIdx.x;
    const int g = p & 3;
    const int h = (p >> 4) + ((p >> 2) & 3) * 16;
    const int row = g*64 + h;
    const float v = (k < 64) ? Wih[row*64 + k] : Whh[row*64 + (k - 64)];
    const int gp = (k >> 3) ^ (p & 15);           // swizzled granule
    wperm[p*128 + gp*8 + (k & 7)] = f2bf(v);
  } else {
    for (int idx = threadIdx.x; idx < 4096; idx += 128) {
      const int lane = idx >> 6, r = idx & 63;
      const int nt = r >> 4, kf = (r >> 3) & 1, j = r & 7;
      const int m = lane & 15, quad = lane >> 4;
      wgp[idx] = f2bf(Wg[(kf*32 + quad*8 + j)*64 + nt*16 + m]);
    }
  }
}

// ---- K1: grid-fused {edge binning | xs = x @ W_gat + att dots | h->bf16} --
__global__ __launch_bounds__(256) void k_binproj(
    const int* __restrict__ ei, int* __restrict__ bcursor,
    unsigned int* __restrict__ binned,
    const float* __restrict__ x, const unsigned short* __restrict__ wgp,
    const float* __restrict__ att_s, const float* __restrict__ att_d,
    unsigned short* __restrict__ xs16, float* __restrict__ a_src,
    float* __restrict__ a_dst,
    const float* __restrict__ h0, unsigned short* __restrict__ h16)
{
  if (blockIdx.x < 256) {
    // ---------------- bin path ----------------
    __shared__ int cnt[NB];
    __shared__ int gbase[NB];
    const int tid = threadIdx.x;
    const size_t base = (size_t)blockIdx.x * 256 * EPB;

    for (int b = tid; b < NB; b += 256) cnt[b] = 0;
    __syncthreads();

    unsigned int pay[EPB];
    int bidx[EPB], pos[EPB];
    #pragma unroll
    for (int j = 0; j < EPB; ++j) {
      const size_t e = base + (size_t)j*256 + tid;
      if (e < EE) {
        const int s = ei[e];
        const int d = ei[EE + e];
        bidx[j] = d >> 6;
        pay[j] = (unsigned)s | ((unsigned)(d & 63) << 17);
        pos[j] = atomicAdd(&cnt[bidx[j]], 1);
      } else {
        bidx[j] = -1;
      }
    }
    __syncthreads();

    for (int b = tid; b < NB; b += 256) {
      const int c = cnt[b];
      gbase[b] = c ? atomicAdd(&bcursor[b*16], c) : 0;
    }
    __syncthreads();

    #pragma unroll
    for (int j = 0; j < EPB; ++j) {
      if (bidx[j] >= 0) {
        const int g = gbase[bidx[j]] + pos[j];
        if (g < CAP) binned[(size_t)bidx[j]*CAP + g] = pay[j];
      }
    }
  } else if (blockIdx.x < 256 + PROJB) {
    // ---------------- proj path ----------------
    const int lane = threadIdx.x & 63;
    const int wave = threadIdx.x >> 6;
    const int tile = (blockIdx.x - 256) * 4 + wave;
    if (tile >= NTILE) return;
    const int m = lane & 15, quad = lane >> 4;

    bf16x8 bfrag[4][2];
    {
      const unsigned short* wp = wgp + lane*64;
      #pragma unroll
      for (int nt = 0; nt < 4; ++nt)
        #pragma unroll
        for (int kf = 0; kf < 2; ++kf)
          bfrag[nt][kf] = *(const bf16x8*)(wp + nt*16 + kf*8);
    }

    const int row = tile*16 + m;
    bf16x8 afrag[2];
    #pragma unroll
    for (int kf = 0; kf < 2; ++kf) {
      const float4* p = (const float4*)(x + (size_t)row*64 + kf*32 + quad*8);
      afrag[kf] = cvt8(p[0], p[1]);
    }

    f32x4 acc[4];
    #pragma unroll
    for (int nt = 0; nt < 4; ++nt) acc[nt] = f32x4{0.f, 0.f, 0.f, 0.f};
    #pragma unroll
    for (int nt = 0; nt < 4; ++nt)
      #pragma unroll
      for (int kf = 0; kf < 2; ++kf)
        acc[nt] = __builtin_amdgcn_mfma_f32_16x16x32_bf16(
            afrag[kf], bfrag[nt][kf], acc[nt], 0, 0, 0);

    float ss[4] = {0.f,0.f,0.f,0.f}, sd[4] = {0.f,0.f,0.f,0.f};
    #pragma unroll
    for (int nt = 0; nt < 4; ++nt) {
      const float av = att_s[nt*16 + m], dv = att_d[nt*16 + m];
      #pragma unroll
      for (int r = 0; r < 4; ++r) {
        const float v = acc[nt][r];
        xs16[(size_t)(tile*16 + quad*4 + r)*64 + nt*16 + m] = f2bf(v);
        ss[r] += v * av;
        sd[r] += v * dv;
      }
    }
    #pragma unroll
    for (int off = 1; off < 16; off <<= 1) {
      #pragma unroll
      for (int r = 0; r < 4; ++r) {
        ss[r] += __shfl_xor(ss[r], off);
        sd[r] += __shfl_xor(sd[r], off);
      }
    }
    if (m == 0) {
      #pragma unroll
      for (int r = 0; r < 4; ++r) {
        a_src[tile*16 + quad*4 + r] = ss[r];
        a_dst[tile*16 + quad*4 + r] = sd[r];
      }
    }
  } else {
    // ---------------- h -> bf16 path ----------------
    const int idx = (blockIdx.x - 256 - PROJB)*256 + threadIdx.x;  // 0..799999
    const float* p = h0 + (size_t)idx*8;
    const bf16x8 v = cvt8(*(const float4*)p, *(const float4*)(p + 4));
    *(bf16x8*)(h16 + (size_t)idx*8) = v;
  }
}

// ---- K3: fused CSR build + softmax aggregation, one block per bucket.
// Round-7: revert round-6 src-sort (falsified: FETCH unchanged, overhead
// real).  Passes 1-3 = round-5 proven form (MLP pass 1, pos packed in bits
// 23+, atomic-free scatter).  Pass 4 = single-stream loop but with 8 groups
// of 8 lanes (uint4/16B per lane): 8 outstanding edge-gathers per wave
// (2x round-4's 4), no predication, half the loop iterations.
__global__ __launch_bounds__(256) void k_agg(
    const int* __restrict__ bcursor, const unsigned int* __restrict__ binned,
    const float* __restrict__ a_src, const float* __restrict__ a_dst,
    const unsigned short* __restrict__ xs16, const float* __restrict__ bias,
    unsigned short* __restrict__ xb16)
{
  __shared__ uint2 raw2[CAP];      // {packed w | pos<<23, p bits}
  __shared__ uint2 csre[CAP];      // {src node, p bits} in CSR order
  __shared__ float zsum[64], invzsh[64], adsh[64];
  __shared__ int cnt[64], offs[64];
  const int b = blockIdx.x;
  const int tid = threadIdx.x;
  const int ne = min(bcursor[b*16], CAP);

  if (tid < 64) {
    cnt[tid] = 0;
    zsum[tid] = 0.f;
    const int node = b*64 + tid;
    adsh[tid] = (node < NN) ? a_dst[node] : 0.f;
  }
  __syncthreads();

  // pass 1: MLP-unrolled edge-parallel p + degree + z  (6*256 >= CAP)
  {
    unsigned int w6[6];
    float as6[6];
    #pragma unroll
    for (int k = 0; k < 6; ++k) {
      const int i = tid + k*256;
      w6[k] = (i < ne) ? binned[(size_t)b*CAP + i] : 0u;
    }
    #pragma unroll
    for (int k = 0; k < 6; ++k) {
      const int i = tid + k*256;
      as6[k] = (i < ne) ? a_src[w6[k] & 0x1FFFFu] : 0.f;
    }
    #pragma unroll
    for (int k = 0; k < 6; ++k) {
      const int i = tid + k*256;
      if (i < ne) {
        const int dl = (int)((w6[k] >> 17) & 63u);
        float ev = as6[k] + adsh[dl];
        ev = (ev >= 0.f) ? ev : 0.2f*ev;
        const float pv = __expf(ev);
        const int pos = atomicAdd(&cnt[dl], 1);   // also = CSR slot within node
        atomicAdd(&zsum[dl], pv);
        raw2[i] = make_uint2((w6[k] & 0x7FFFFFu) | ((unsigned)pos << 23),
                             __float_as_uint(pv));
      }
    }
  }
  __syncthreads();

  // pass 2: prefix sum + per-node 1/z
  if (tid < 64) {
    const int v = cnt[tid];
    int inc = v;
    #pragma unroll
    for (int dd = 1; dd < 64; dd <<= 1) {
      const int o = __shfl_up(inc, dd, 64);
      if (tid >= dd) inc += o;
    }
    offs[tid] = inc - v;
    invzsh[tid] = 1.f / (zsum[tid] + 1e-16f);
  }
  __syncthreads();

  // pass 3: atomic-free scatter {s,p} to CSR order
  #pragma unroll
  for (int k = 0; k < 6; ++k) {
    const int i = tid + k*256;
    if (i < ne) {
      const uint2 r = raw2[i];
      const int dl = (int)((r.x >> 17) & 63u);
      const int pos = (int)(r.x >> 23);
      csre[offs[dl] + pos] = make_uint2(r.x & 0x1FFFFu, r.y);
    }
  }
  __syncthreads();

  // pass 4: aggregation, 8 lane-groups of 8 -> 8 edges in flight per wave
  const int lane = tid & 63;
  const int wv = tid >> 6;
  const int grp = lane >> 3, l8 = lane & 7;
  const float4 b4a = *(const float4*)(bias + l8*8);
  const float4 b4b = *(const float4*)(bias + l8*8 + 4);
  const unsigned short* xrow = xs16 + l8*8;
  for (int t = 0; t < 16; ++t) {
    const int nl = wv*16 + t;
    const int node = b*64 + nl;
    if (node >= NN) break;
    const int bse = offs[nl];
    const int dg = cnt[nl];
    float a0=0.f,a1=0.f,a2=0.f,a3=0.f,a4=0.f,a5=0.f,a6=0.f,a7=0.f;
    for (int e = grp; e < dg; e += 8) {
      const uint2 sp = csre[bse + e];
      const float pv = __uint_as_float(sp.y);
      const uint4 rw = *(const uint4*)(xrow + (size_t)sp.x*64);
      a0 += pv*bflo(rw.x); a1 += pv*bfhi(rw.x);
      a2 += pv*bflo(rw.y); a3 += pv*bfhi(rw.y);
      a4 += pv*bflo(rw.z); a5 += pv*bfhi(rw.z);
      a6 += pv*bflo(rw.w); a7 += pv*bfhi(rw.w);
    }
    #pragma unroll
    for (int off = 8; off < 64; off <<= 1) {
      a0 += __shfl_xor(a0, off); a1 += __shfl_xor(a1, off);
      a2 += __shfl_xor(a2, off); a3 += __shfl_xor(a3, off);
      a4 += __shfl_xor(a4, off); a5 += __shfl_xor(a5, off);
      a6 += __shfl_xor(a6, off); a7 += __shfl_xor(a7, off);
    }
    if (lane < 8) {
      const float invz = invzsh[nl];
      uint4 o;
      o.x = (unsigned)f2bf(tanhfast(a0*invz + b4a.x)) |
            ((unsigned)f2bf(tanhfast(a1*invz + b4a.y)) << 16);
      o.y = (unsigned)f2bf(tanhfast(a2*invz + b4a.z)) |
            ((unsigned)f2bf(tanhfast(a3*invz + b4a.w)) << 16);
      o.z = (unsigned)f2bf(tanhfast(a4*invz + b4b.x)) |
            ((unsigned)f2bf(tanhfast(a5*invz + b4b.y)) << 16);
      o.w = (unsigned)f2bf(tanhfast(a6*invz + b4b.z)) |
            ((unsigned)f2bf(tanhfast(a7*invz + b4b.w)) << 16);
      *(uint4*)(xb16 + (size_t)node*64 + l8*8) = o;
    }
  }
}

// ---- K4: LSTM with LDS-resident weights (unchanged from round 3).
__global__ __launch_bounds__(1024, 2) void k_lstm(
    const unsigned short* __restrict__ xb16, const unsigned short* __restrict__ h16,
    const float* __restrict__ c0, const unsigned short* __restrict__ wperm,
    float* __restrict__ out)
{
  __shared__ unsigned short wlds[256*128];   // 64 KB, swizzled layout
  const int tid = threadIdx.x;
  {
    const float4* gs = (const float4*)wperm;
    float4* ls = (float4*)wlds;
    #pragma unroll
    for (int i = 0; i < 4; ++i) ls[tid + i*1024] = gs[tid + i*1024];
  }
  __syncthreads();

  const int w = tid >> 6, lane = tid & 63;
  const int wv = w & 3, tsub = w >> 2;
  const int m = lane & 15, quad = lane >> 4;
  const int tile = blockIdx.x*4 + tsub;
  if (tile >= NTILE) return;
  const int node = tile*16 + m;

  bf16x8 bfr[4];
  bfr[0] = *(const bf16x8*)(xb16 + (size_t)node*64 + quad*8);
  bfr[1] = *(const bf16x8*)(xb16 + (size_t)node*64 + 32 + quad*8);
  bfr[2] = *(const bf16x8*)(h16 + (size_t)node*64 + quad*8);
  bfr[3] = *(const bf16x8*)(h16 + (size_t)node*64 + 32 + quad*8);

  const int q32 = (m >> 2) & 3;
  const int base = (wv*64 + m)*256 + ((quad ^ (m & 3)) << 4);
  const char* lb = (const char*)wlds;
  const int a0 = base + ((0 ^ q32) << 6);
  const int a1 = base + ((1 ^ q32) << 6);
  const int a2 = base + ((2 ^ q32) << 6);
  const int a3 = base + ((3 ^ q32) << 6);

  f32x4 acc[4];
  #pragma unroll
  for (int u = 0; u < 4; ++u) acc[u] = f32x4{0.f, 0.f, 0.f, 0.f};
  #pragma unroll
  for (int u = 0; u < 4; ++u) {
    const int uo = u*4096;
    const bf16x8 w0 = *(const bf16x8*)(lb + a0 + uo);
    const bf16x8 w1 = *(const bf16x8*)(lb + a1 + uo);
    const bf16x8 w2 = *(const bf16x8*)(lb + a2 + uo);
    const bf16x8 w3 = *(const bf16x8*)(lb + a3 + uo);
    acc[u] = __builtin_amdgcn_mfma_f32_16x16x32_bf16(w0, bfr[0], acc[u], 0, 0, 0);
    acc[u] = __builtin_amdgcn_mfma_f32_16x16x32_bf16(w1, bfr[1], acc[u], 0, 0, 0);
    acc[u] = __builtin_amdgcn_mfma_f32_16x16x32_bf16(w2, bfr[2], acc[u], 0, 0, 0);
    acc[u] = __builtin_amdgcn_mfma_f32_16x16x32_bf16(w3, bfr[3], acc[u], 0, 0, 0);
  }

  const size_t obase = (size_t)node*64 + quad*16 + wv*4;
  const float4 cv = *(const float4*)(c0 + obase);
  const float cvv[4] = {cv.x, cv.y, cv.z, cv.w};
  float h1a[4], c1a[4];
  #pragma unroll
  for (int u = 0; u < 4; ++u) {
    const float gi = acc[u][0], gf = acc[u][1];
    const float gg = acc[u][2], go = acc[u][3];
    const float c1 = sigmoidf_(gf)*cvv[u] + sigmoidf_(gi)*tanhfast(gg);
    h1a[u] = sigmoidf_(go)*tanhfast(c1);
    c1a[u] = c1;
  }
  const float4 hv  = make_float4(h1a[0], h1a[1], h1a[2], h1a[3]);
  const float4 c1v = make_float4(c1a[0], c1a[1], c1a[2], c1a[3]);
  *(float4*)(out + obase) = hv;
  *(float4*)(out + (size_t)NN*64 + obase) = hv;
  *(float4*)(out + (size_t)2*NN*64 + obase) = c1v;
}

// ---------------- launch ---------------------------------------------------
extern "C" void kernel_launch(void* const* d_in, const int* in_sizes, int n_in,
                              void* d_out, int out_size, void* d_ws, size_t ws_size,
                              hipStream_t stream) {
  const float* x    = (const float*)d_in[0];
  const int*   ei   = (const int*)d_in[1];
  const float* h    = (const float*)d_in[2];
  const float* c    = (const float*)d_in[3];
  const float* Wg   = (const float*)d_in[4];
  const float* atts = (const float*)d_in[5];
  const float* attd = (const float*)d_in[6];
  const float* bg   = (const float*)d_in[7];
  const float* Wih  = (const float*)d_in[8];
  const float* Whh  = (const float*)d_in[9];
  float* out = (float*)d_out;

  char* w = (char*)d_ws;
  unsigned short* xs16  = (unsigned short*)w; w += (size_t)NN*64*2;
  unsigned short* xb16  = (unsigned short*)w; w += (size_t)NN*64*2;
  unsigned short* h16   = (unsigned short*)w; w += (size_t)NN*64*2;
  unsigned short* wperm = (unsigned short*)w; w += (size_t)256*128*2;
  unsigned short* wgp   = (unsigned short*)w; w += (size_t)4096*2;
  unsigned int*   binned= (unsigned int*)w;  w += (size_t)NB*CAP*4;
  float* a_src = (float*)w; w += (size_t)NN*4;
  float* a_dst = (float*)w; w += (size_t)NN*4;
  int* bcursor = (int*)w;   w += (size_t)NB*16*4;   // 64B-padded cursors

  hipMemsetAsync(bcursor, 0, (size_t)NB*16*4, stream);

  k_prep    <<<257, 128, 0, stream>>>(Wih, Whh, Wg, wperm, wgp);
  k_binproj <<<256 + PROJB + CVTB, 256, 0, stream>>>(
      ei, bcursor, binned, x, wgp, atts, attd, xs16, a_src, a_dst, h, h16);
  k_agg     <<<NB, 256, 0, stream>>>(bcursor, binned, a_src, a_dst, xs16, bg, xb16);
  k_lstm    <<<PROJB, 1024, 0, stream>>>(xb16, h16, c, wperm, out);
}

// Round 8
// 293.829 us; speedup vs baseline: 1.0780x; 1.0341x over previous
//
#include <hip/hip_runtime.h>
#include <cmath>

#define NN 100000
#define EE 1600000
#define NB 1563          // ceil(NN/64) buckets of 64 dst nodes
#define CAP 1344         // per-bucket edge capacity (mean 1024, sigma 32)
#define EPB 25           // edges per thread in bin path (256 blk * 256 thr * 25)
#define NTILE 6250       // NN/16
#define PROJB 1563       // ceil(NTILE/4) proj blocks
#define CVTB 3125        // h->bf16 conversion blocks (256 thr * 8 elems)

using bf16x8 = __attribute__((ext_vector_type(8))) __bf16;
using f32x4  = __attribute__((ext_vector_type(4))) float;

__device__ __forceinline__ unsigned short f2bf(float f) {
  __bf16 b = (__bf16)f;
  return __builtin_bit_cast(unsigned short, b);
}
__device__ __forceinline__ float bflo(unsigned int u) {
  return __uint_as_float(u << 16);
}
__device__ __forceinline__ float bfhi(unsigned int u) {
  return __uint_as_float(u & 0xffff0000u);
}
__device__ __forceinline__ float sigmoidf_(float v) {
  return 1.0f / (1.0f + __expf(-v));
}
// fast tanh: exact at +-inf, ~1e-6 abs err, far below bf16 quantization
__device__ __forceinline__ float tanhfast(float v) {
  return 1.0f - 2.0f / (1.0f + __expf(2.0f * v));
}
__device__ __forceinline__ bf16x8 cvt8(float4 a, float4 b) {
  bf16x8 r;
  r[0]=(__bf16)a.x; r[1]=(__bf16)a.y; r[2]=(__bf16)a.z; r[3]=(__bf16)a.w;
  r[4]=(__bf16)b.x; r[5]=(__bf16)b.y; r[6]=(__bf16)b.z; r[7]=(__bf16)b.w;
  return r;
}

// ---- K0: weight prep ----
// wperm rows are stored GRANULE-SWIZZLED for conflict-free LDS reads in
// k_lstm: logical 16B granule gl = kf*4+quad of row p lives at physical
// granule gl ^ (p&15).  (Linear global->LDS copy preserves the swizzle.)
__global__ __launch_bounds__(128) void k_prep(
    const float* __restrict__ Wih, const float* __restrict__ Whh,
    const float* __restrict__ Wg,
    unsigned short* __restrict__ wperm, unsigned short* __restrict__ wgp)
{
  if (blockIdx.x < 256) {
    const int p = blockIdx.x, k = threadIdx.x;
    const int g = p & 3;
    const int h = (p >> 4) + ((p >> 2) & 3) * 16;
    const int row = g*64 + h;
    const float v = (k < 64) ? Wih[row*64 + k] : Whh[row*64 + (k - 64)];
    const int gp = (k >> 3) ^ (p & 15);           // swizzled granule
    wperm[p*128 + gp*8 + (k & 7)] = f2bf(v);
  } else {
    for (int idx = threadIdx.x; idx < 4096; idx += 128) {
      const int lane = idx >> 6, r = idx & 63;
      const int nt = r >> 4, kf = (r >> 3) & 1, j = r & 7;
      const int m = lane & 15, quad = lane >> 4;
      wgp[idx] = f2bf(Wg[(kf*32 + quad*8 + j)*64 + nt*16 + m]);
    }
  }
}

// ---- K1: grid-fused {edge binning | xs = x @ W_gat + att dots | h->bf16} --
__global__ __launch_bounds__(256) void k_binproj(
    const int* __restrict__ ei, int* __restrict__ bcursor,
    unsigned int* __restrict__ binned,
    const float* __restrict__ x, const unsigned short* __restrict__ wgp,
    const float* __restrict__ att_s, const float* __restrict__ att_d,
    unsigned short* __restrict__ xs16, float* __restrict__ a_src,
    float* __restrict__ a_dst,
    const float* __restrict__ h0, unsigned short* __restrict__ h16)
{
  if (blockIdx.x < 256) {
    // ---------------- bin path ----------------
    __shared__ int cnt[NB];
    __shared__ int gbase[NB];
    const int tid = threadIdx.x;
    const size_t base = (size_t)blockIdx.x * 256 * EPB;

    for (int b = tid; b < NB; b += 256) cnt[b] = 0;
    __syncthreads();

    unsigned int pay[EPB];
    int bidx[EPB], pos[EPB];
    #pragma unroll
    for (int j = 0; j < EPB; ++j) {
      const size_t e = base + (size_t)j*256 + tid;
      if (e < EE) {
        const int s = ei[e];
        const int d = ei[EE + e];
        bidx[j] = d >> 6;
        pay[j] = (unsigned)s | ((unsigned)(d & 63) << 17);
        pos[j] = atomicAdd(&cnt[bidx[j]], 1);
      } else {
        bidx[j] = -1;
      }
    }
    __syncthreads();

    for (int b = tid; b < NB; b += 256) {
      const int c = cnt[b];
      gbase[b] = c ? atomicAdd(&bcursor[b*16], c) : 0;
    }
    __syncthreads();

    #pragma unroll
    for (int j = 0; j < EPB; ++j) {
      if (bidx[j] >= 0) {
        const int g = gbase[bidx[j]] + pos[j];
        if (g < CAP) binned[(size_t)bidx[j]*CAP + g] = pay[j];
      }
    }
  } else if (blockIdx.x < 256 + PROJB) {
    // ---------------- proj path ----------------
    const int lane = threadIdx.x & 63;
    const int wave = threadIdx.x >> 6;
    const int tile = (blockIdx.x - 256) * 4 + wave;
    if (tile >= NTILE) return;
    const int m = lane & 15, quad = lane >> 4;

    bf16x8 bfrag[4][2];
    {
      const unsigned short* wp = wgp + lane*64;
      #pragma unroll
      for (int nt = 0; nt < 4; ++nt)
        #pragma unroll
        for (int kf = 0; kf < 2; ++kf)
          bfrag[nt][kf] = *(const bf16x8*)(wp + nt*16 + kf*8);
    }

    const int row = tile*16 + m;
    bf16x8 afrag[2];
    #pragma unroll
    for (int kf = 0; kf < 2; ++kf) {
      const float4* p = (const float4*)(x + (size_t)row*64 + kf*32 + quad*8);
      afrag[kf] = cvt8(p[0], p[1]);
    }

    f32x4 acc[4];
    #pragma unroll
    for (int nt = 0; nt < 4; ++nt) acc[nt] = f32x4{0.f, 0.f, 0.f, 0.f};
    #pragma unroll
    for (int nt = 0; nt < 4; ++nt)
      #pragma unroll
      for (int kf = 0; kf < 2; ++kf)
        acc[nt] = __builtin_amdgcn_mfma_f32_16x16x32_bf16(
            afrag[kf], bfrag[nt][kf], acc[nt], 0, 0, 0);

    float ss[4] = {0.f,0.f,0.f,0.f}, sd[4] = {0.f,0.f,0.f,0.f};
    #pragma unroll
    for (int nt = 0; nt < 4; ++nt) {
      const float av = att_s[nt*16 + m], dv = att_d[nt*16 + m];
      #pragma unroll
      for (int r = 0; r < 4; ++r) {
        const float v = acc[nt][r];
        xs16[(size_t)(tile*16 + quad*4 + r)*64 + nt*16 + m] = f2bf(v);
        ss[r] += v * av;
        sd[r] += v * dv;
      }
    }
    #pragma unroll
    for (int off = 1; off < 16; off <<= 1) {
      #pragma unroll
      for (int r = 0; r < 4; ++r) {
        ss[r] += __shfl_xor(ss[r], off);
        sd[r] += __shfl_xor(sd[r], off);
      }
    }
    if (m == 0) {
      #pragma unroll
      for (int r = 0; r < 4; ++r) {
        a_src[tile*16 + quad*4 + r] = ss[r];
        a_dst[tile*16 + quad*4 + r] = sd[r];
      }
    }
  } else {
    // ---------------- h -> bf16 path ----------------
    const int idx = (blockIdx.x - 256 - PROJB)*256 + threadIdx.x;  // 0..799999
    const float* p = h0 + (size_t)idx*8;
    const bf16x8 v = cvt8(*(const float4*)p, *(const float4*)(p + 4));
    *(bf16x8*)(h16 + (size_t)idx*8) = v;
  }
}

// ---- K3: fused CSR build + softmax aggregation, one block per bucket.
// Round-8: occupancy attack.  {w, pv} carried in REGISTERS across the
// barriers (same thread owns edge i in passes 1 and 3), so raw2/parray
// LDS staging is gone: 23 KB -> ~12.4 KB LDS.  Blocks/CU 6 -> 8
// (wave-capped); entire 1563-block grid co-resident.  Pass 4 = proven
// round-4 form + 2-deep csre prefetch (csre padded so the prefetch
// never leaves the array).
__global__ __launch_bounds__(256) void k_agg(
    const int* __restrict__ bcursor, const unsigned int* __restrict__ binned,
    const float* __restrict__ a_src, const float* __restrict__ a_dst,
    const unsigned short* __restrict__ xs16, const float* __restrict__ bias,
    unsigned short* __restrict__ xb16)
{
  __shared__ uint2 csre[CAP + 8];  // {src node, p bits} in CSR order (+pad)
  __shared__ float zsum[64], invzsh[64], adsh[64];
  __shared__ int cnt[64], offs[64], cursor[64];
  const int b = blockIdx.x;
  const int tid = threadIdx.x;
  const int ne = min(bcursor[b*16], CAP);

  if (tid < 64) {
    cnt[tid] = 0;
    zsum[tid] = 0.f;
    const int node = b*64 + tid;
    adsh[tid] = (node < NN) ? a_dst[node] : 0.f;
  }
  __syncthreads();

  // pass 1: MLP-unrolled edge-parallel p + degree + z  (6*256 >= CAP).
  // w6/pv6 stay live in registers until pass 3.
  unsigned int w6[6];
  float pv6[6];
  {
    float as6[6];
    #pragma unroll
    for (int k = 0; k < 6; ++k) {
      const int i = tid + k*256;
      w6[k] = (i < ne) ? binned[(size_t)b*CAP + i] : 0u;
    }
    #pragma unroll
    for (int k = 0; k < 6; ++k) {
      const int i = tid + k*256;
      as6[k] = (i < ne) ? a_src[w6[k] & 0x1FFFFu] : 0.f;
    }
    #pragma unroll
    for (int k = 0; k < 6; ++k) {
      const int i = tid + k*256;
      if (i < ne) {
        const int dl = (int)((w6[k] >> 17) & 63u);
        float ev = as6[k] + adsh[dl];
        ev = (ev >= 0.f) ? ev : 0.2f*ev;
        const float pv = __expf(ev);
        pv6[k] = pv;
        atomicAdd(&cnt[dl], 1);
        atomicAdd(&zsum[dl], pv);
      }
    }
  }
  __syncthreads();

  // pass 2: prefix sum + per-node 1/z
  if (tid < 64) {
    const int v = cnt[tid];
    int inc = v;
    #pragma unroll
    for (int dd = 1; dd < 64; dd <<= 1) {
      const int o = __shfl_up(inc, dd, 64);
      if (tid >= dd) inc += o;
    }
    offs[tid] = inc - v;
    cursor[tid] = inc - v;
    invzsh[tid] = 1.f / (zsum[tid] + 1e-16f);
  }
  __syncthreads();

  // pass 3: scatter {s,p} from registers to CSR order
  #pragma unroll
  for (int k = 0; k < 6; ++k) {
    const int i = tid + k*256;
    if (i < ne) {
      const unsigned int w = w6[k];
      const int dl = (int)((w >> 17) & 63u);
      const int pos = atomicAdd(&cursor[dl], 1);
      csre[pos] = make_uint2(w & 0x1FFFFu, __float_as_uint(pv6[k]));
    }
  }
  __syncthreads();

  // pass 4: aggregation (round-4 form) + 2-deep csre prefetch
  const int lane = tid & 63;
  const int wv = tid >> 6;
  const int grp = lane >> 4, l16 = lane & 15;
  const float4 b4 = *(const float4*)(bias + l16*4);
  const unsigned short* xrow = xs16 + l16*4;
  for (int t = 0; t < 16; ++t) {
    const int nl = wv*16 + t;
    const int node = b*64 + nl;
    if (node >= NN) break;
    const int bse = offs[nl];
    const int dg = cnt[nl];
    float acc0=0.f, acc1=0.f, acc2=0.f, acc3=0.f;
    uint2 sp = csre[bse + grp];
    for (int e = grp; e < dg; e += 4) {
      const uint2 spn = csre[bse + e + 4];   // prefetch next (pad-safe)
      const float pv = __uint_as_float(sp.y);
      const uint2 rw = *(const uint2*)(xrow + (size_t)sp.x*64);
      acc0 += pv*bflo(rw.x); acc1 += pv*bfhi(rw.x);
      acc2 += pv*bflo(rw.y); acc3 += pv*bfhi(rw.y);
      sp = spn;
    }
    #pragma unroll
    for (int off = 16; off < 64; off <<= 1) {
      acc0 += __shfl_xor(acc0, off);
      acc1 += __shfl_xor(acc1, off);
      acc2 += __shfl_xor(acc2, off);
      acc3 += __shfl_xor(acc3, off);
    }
    if (lane < 16) {
      const float invz = invzsh[nl];
      ushort4 o;
      o.x = f2bf(tanhfast(acc0*invz + b4.x));
      o.y = f2bf(tanhfast(acc1*invz + b4.y));
      o.z = f2bf(tanhfast(acc2*invz + b4.z));
      o.w = f2bf(tanhfast(acc3*invz + b4.w));
      *(ushort4*)(xb16 + (size_t)node*64 + l16*4) = o;
    }
  }
}

// ---- K4: LSTM with LDS-resident weights.
// Round-8: grid-stride with grid=512 (= the 2-blocks/CU residency at 64 KB
// LDS).  Weights staged once per block, amortized over ~3 tile-groups
// (staging traffic 100 MB -> 33 MB; block launch/drain rounds 3 -> 1).
__global__ __launch_bounds__(1024, 2) void k_lstm(
    const unsigned short* __restrict__ xb16, const unsigned short* __restrict__ h16,
    const float* __restrict__ c0, const unsigned short* __restrict__ wperm,
    float* __restrict__ out)
{
  __shared__ unsigned short wlds[256*128];   // 64 KB, swizzled layout
  const int tid = threadIdx.x;
  {
    const float4* gs = (const float4*)wperm;
    float4* ls = (float4*)wlds;
    #pragma unroll
    for (int i = 0; i < 4; ++i) ls[tid + i*1024] = gs[tid + i*1024];
  }
  __syncthreads();

  const int w = tid >> 6, lane = tid & 63;
  const int wv = w & 3, tsub = w >> 2;
  const int m = lane & 15, quad = lane >> 4;

  // physical LDS weight addresses (tile-independent, hoisted)
  const int q32 = (m >> 2) & 3;
  const int base = (wv*64 + m)*256 + ((quad ^ (m & 3)) << 4);
  const char* lb = (const char*)wlds;
  const int a0 = base + ((0 ^ q32) << 6);
  const int a1 = base + ((1 ^ q32) << 6);
  const int a2 = base + ((2 ^ q32) << 6);
  const int a3 = base + ((3 ^ q32) << 6);

  for (int tg = blockIdx.x; tg < PROJB; tg += gridDim.x) {
    const int tile = tg*4 + tsub;
    if (tile >= NTILE) continue;
    const int node = tile*16 + m;

    bf16x8 bfr[4];
    bfr[0] = *(const bf16x8*)(xb16 + (size_t)node*64 + quad*8);
    bfr[1] = *(const bf16x8*)(xb16 + (size_t)node*64 + 32 + quad*8);
    bfr[2] = *(const bf16x8*)(h16 + (size_t)node*64 + quad*8);
    bfr[3] = *(const bf16x8*)(h16 + (size_t)node*64 + 32 + quad*8);

    f32x4 acc[4];
    #pragma unroll
    for (int u = 0; u < 4; ++u) acc[u] = f32x4{0.f, 0.f, 0.f, 0.f};
    #pragma unroll
    for (int u = 0; u < 4; ++u) {
      const int uo = u*4096;
      const bf16x8 w0 = *(const bf16x8*)(lb + a0 + uo);
      const bf16x8 w1 = *(const bf16x8*)(lb + a1 + uo);
      const bf16x8 w2 = *(const bf16x8*)(lb + a2 + uo);
      const bf16x8 w3 = *(const bf16x8*)(lb + a3 + uo);
      acc[u] = __builtin_amdgcn_mfma_f32_16x16x32_bf16(w0, bfr[0], acc[u], 0, 0, 0);
      acc[u] = __builtin_amdgcn_mfma_f32_16x16x32_bf16(w1, bfr[1], acc[u], 0, 0, 0);
      acc[u] = __builtin_amdgcn_mfma_f32_16x16x32_bf16(w2, bfr[2], acc[u], 0, 0, 0);
      acc[u] = __builtin_amdgcn_mfma_f32_16x16x32_bf16(w3, bfr[3], acc[u], 0, 0, 0);
    }

    const size_t obase = (size_t)node*64 + quad*16 + wv*4;
    const float4 cv = *(const float4*)(c0 + obase);
    const float cvv[4] = {cv.x, cv.y, cv.z, cv.w};
    float h1a[4], c1a[4];
    #pragma unroll
    for (int u = 0; u < 4; ++u) {
      const float gi = acc[u][0], gf = acc[u][1];
      const float gg = acc[u][2], go = acc[u][3];
      const float c1 = sigmoidf_(gf)*cvv[u] + sigmoidf_(gi)*tanhfast(gg);
      h1a[u] = sigmoidf_(go)*tanhfast(c1);
      c1a[u] = c1;
    }
    const float4 hv  = make_float4(h1a[0], h1a[1], h1a[2], h1a[3]);
    const float4 c1v = make_float4(c1a[0], c1a[1], c1a[2], c1a[3]);
    *(float4*)(out + obase) = hv;
    *(float4*)(out + (size_t)NN*64 + obase) = hv;
    *(float4*)(out + (size_t)2*NN*64 + obase) = c1v;
  }
}

// ---------------- launch ---------------------------------------------------
extern "C" void kernel_launch(void* const* d_in, const int* in_sizes, int n_in,
                              void* d_out, int out_size, void* d_ws, size_t ws_size,
                              hipStream_t stream) {
  const float* x    = (const float*)d_in[0];
  const int*   ei   = (const int*)d_in[1];
  const float* h    = (const float*)d_in[2];
  const float* c    = (const float*)d_in[3];
  const float* Wg   = (const float*)d_in[4];
  const float* atts = (const float*)d_in[5];
  const float* attd = (const float*)d_in[6];
  const float* bg   = (const float*)d_in[7];
  const float* Wih  = (const float*)d_in[8];
  const float* Whh  = (const float*)d_in[9];
  float* out = (float*)d_out;

  char* w = (char*)d_ws;
  unsigned short* xs16  = (unsigned short*)w; w += (size_t)NN*64*2;
  unsigned short* xb16  = (unsigned short*)w; w += (size_t)NN*64*2;
  unsigned short* h16   = (unsigned short*)w; w += (size_t)NN*64*2;
  unsigned short* wperm = (unsigned short*)w; w += (size_t)256*128*2;
  unsigned short* wgp   = (unsigned short*)w; w += (size_t)4096*2;
  unsigned int*   binned= (unsigned int*)w;  w += (size_t)NB*CAP*4;
  float* a_src = (float*)w; w += (size_t)NN*4;
  float* a_dst = (float*)w; w += (size_t)NN*4;
  int* bcursor = (int*)w;   w += (size_t)NB*16*4;   // 64B-padded cursors

  hipMemsetAsync(bcursor, 0, (size_t)NB*16*4, stream);

  k_prep    <<<257, 128, 0, stream>>>(Wih, Whh, Wg, wperm, wgp);
  k_binproj <<<256 + PROJB + CVTB, 256, 0, stream>>>(
      ei, bcursor, binned, x, wgp, atts, attd, xs16, a_src, a_dst, h, h16);
  k_agg     <<<NB, 256, 0, stream>>>(bcursor, binned, a_src, a_dst, xs16, bg, xb16);
  k_lstm    <<<512, 1024, 0, stream>>>(xb16, h16, c, wperm, out);
}